// Round 1
// baseline (85.326 us; speedup 1.0000x reference)
//
#include <hip/hip_runtime.h>

// Problem constants
#define NP 256     // particles per (bs, h) slice: (2564-4)/10
#define OD 10      // OBS_DIM
#define ROWLEN 2564
#define NB 512     // bs*horizon = 16*32

// One block per (bs*h) slice b in [0,512), one thread per particle t in [0,256).
// ws layout: ws[0..511]  = per-block chamfer sums of (3*d1 + d2)
//            ws[512..1023] = per-block weighted action L1 (h==1 row ×10)
__global__ __launch_bounds__(256) void cham_main(const float* __restrict__ preds,
                                                 const float* __restrict__ targ,
                                                 float* __restrict__ ws) {
    const int b = blockIdx.x;
    const int t = threadIdx.x;
    const int base = b * ROWLEN;

    // feature dims 5:9 of each particle, stored [d][particle] so inner-loop
    // reads sX[d][k] are wave-uniform broadcasts (conflict-free).
    __shared__ float sA[4][NP];
    __shared__ float sB[4][NP];

    float rA[4], rB[4];
#pragma unroll
    for (int d = 0; d < 4; ++d) {
        float a  = preds[base + 4 + t * OD + 5 + d];
        float bb = targ [base + 4 + t * OD + 5 + d];
        sA[d][t] = a;
        sB[d][t] = bb;
        rA[d] = a;
        rB[d] = bb;
    }
    __syncthreads();

    // Fused dual argmin over the 256x256 squared-distance matrix P:
    //   idx2[t] = argmin_k P[t, k]   (t as pred row i, axis=2 argmin)
    //   idx1[t] = argmin_k P[k, t]   (t as targ col j, axis=1 argmin)
    // Strict < with increasing k == first-index tie-break (matches jnp.argmin).
    float best2 = 3.4e38f, best1 = 3.4e38f;
    int idx2 = 0, idx1 = 0;
#pragma unroll 4
    for (int k = 0; k < NP; ++k) {
        float d2 = 0.f, d1 = 0.f;
#pragma unroll
        for (int d = 0; d < 4; ++d) {
            float va = rA[d] - sB[d][k];
            float vb = sA[d][k] - rB[d];
            d2 = fmaf(va, va, d2);
            d1 = fmaf(vb, vb, d1);
        }
        if (d2 < best2) { best2 = d2; idx2 = k; }
        if (d1 < best1) { best1 = d1; idx1 = k; }
    }

    // Chamfer L1 terms over all 10 obs dims.
    //   particle_dist1[b, t] = sum_d |obs[b, idx1[t], d] - obs_targ[b, t, d]|
    //   particle_dist2[b, t] = sum_d |obs_targ[b, idx2[t], d] - obs[b, t, d]|
    const int ob = base + 4;
    float s1 = 0.f, s2 = 0.f;
#pragma unroll
    for (int d = 0; d < OD; ++d) {
        float o_t   = preds[ob + t * OD + d];
        float ot_t  = targ [ob + t * OD + d];
        float o_i1  = preds[ob + idx1 * OD + d];
        float ot_i2 = targ [ob + idx2 * OD + d];
        s1 += fabsf(o_i1 - ot_t);
        s2 += fabsf(ot_i2 - o_t);
    }
    float v = 3.0f * s1 + s2;

    // Block reduce: wave64 shuffle then cross-wave via LDS.
#pragma unroll
    for (int off = 32; off > 0; off >>= 1) v += __shfl_down(v, off, 64);

    __shared__ float wsum[4];
    if ((t & 63) == 0) wsum[t >> 6] = v;
    __syncthreads();
    if (t == 0) {
        ws[b] = wsum[0] + wsum[1] + wsum[2] + wsum[3];
        // action L1 for this (bs, h): first 4 channels.
        float l1 = 0.f;
#pragma unroll
        for (int d = 0; d < 4; ++d) l1 += fabsf(preds[base + d] - targ[base + d]);
        l1 *= 0.25f;
        const int h = b & 31;
        ws[NB + b] = (h == 1) ? l1 * 10.0f : l1;
    }
}

__global__ __launch_bounds__(512) void cham_final(const float* __restrict__ ws,
                                                  float* __restrict__ out) {
    const int t = threadIdx.x;
    float cham = ws[t];
    float act  = ws[NB + t];
    // a0_loss uses the UNWEIGHTED h==1 values; weighted stored, so ×0.1.
    float a0 = ((t & 31) == 1) ? act * 0.1f : 0.f;

#pragma unroll
    for (int off = 32; off > 0; off >>= 1) {
        cham += __shfl_down(cham, off, 64);
        act  += __shfl_down(act,  off, 64);
        a0   += __shfl_down(a0,   off, 64);
    }
    __shared__ float sc[8], sa[8], s0[8];
    if ((t & 63) == 0) { int w = t >> 6; sc[w] = cham; sa[w] = act; s0[w] = a0; }
    __syncthreads();
    if (t == 0) {
        float C = 0.f, A = 0.f, Z = 0.f;
#pragma unroll
        for (int w = 0; w < 8; ++w) { C += sc[w]; A += sa[w]; Z += s0[w]; }
        // chamfer.mean() = sum(3*d1+d2) / (TARGET_WEIGHT+1) / (512*256*10)
        const float cham_mean = C * (1.0f / (4.0f * (float)NB * (float)NP * (float)OD));
        out[0] = A * (1.0f / (float)NB) + cham_mean;  // loss
        out[1] = Z * (1.0f / 16.0f);                  // a0_loss
    }
}

extern "C" void kernel_launch(void* const* d_in, const int* in_sizes, int n_in,
                              void* d_out, int out_size, void* d_ws, size_t ws_size,
                              hipStream_t stream) {
    const float* preds = (const float*)d_in[0];
    const float* targ  = (const float*)d_in[1];
    float* ws  = (float*)d_ws;
    float* out = (float*)d_out;

    cham_main <<<NB, 256, 0, stream>>>(preds, targ, ws);
    cham_final<<<1, 512, 0, stream>>>(ws, out);
}